// Round 12
// baseline (27.624 us; speedup 1.0000x reference)
//
#include <hip/hip_runtime.h>
#include <math.h>

#define N_  4
#define C_  3
#define H_  540
#define W_  960
#define HO_ 1080
#define WO_ 1920

typedef float f32x4 __attribute__((ext_vector_type(4)));
typedef float f32x2 __attribute__((ext_vector_type(2)));

// Thread = (n, c, ly4, tx): owns low-res rows 4ly4..4ly4+3 x cols [4tx,4tx+4)
// -> output rows 8ly4..8ly4+7, cols [8tx, 8tx+8): 64 px, 16 f32x4 stores.
// Needs input rows 4ly4-1 .. 4ly4+4 (6 clamped rows x 6 clamped cols).
// w[k] holds input row ly0-1+k; low-res row lr=ly0+h uses pool rows w[h..h+2],
// bilinear rows (w[h],w[h+1]) if up else (w[h+1],w[h+2]), z row = w[h+1].
// Clamped loads make border-excluded 3x3 pools == plain min/max over the window.
//
// Ladder: R2 33.2 | R3 +XCD swizzle 30.0 | R5 nt stores 33.7 (REGR) | R6 8-col
// x-tile 42.0 (REGR - VGPR cliff: x-widening doubles ALL transient arrays) |
// R7 y-blend-first trim 28.0 | R8 packed-f32 28.0 (NEUT) | R9 edge shuffles
// 28.9 (REGR) | R10 y*2 tile 26.7 (MATCHED - latency amortization is the lever).
// R11: y*4 tile - 6 input rows serve 8 output rows (1.5 rows-loaded per
// row-consumed vs 2.0), x-consts amortized 8x, per-pixel transients unchanged.
__global__ __launch_bounds__(256) void taa_fused_kernel(
    const float* __restrict__ frame,
    const float* __restrict__ jitter,
    float* __restrict__ out,
    int total_threads, int n_blocks, long long out_elems)
{
    // ---- bijective chunked XCD swizzle (nwg = n_blocks, 8 XCDs)
    int b   = blockIdx.x;
    int q   = n_blocks >> 3, r = n_blocks & 7;
    int xcd = b & 7, i = b >> 3;
    int wb  = (xcd < r ? xcd * (q + 1) : r * (q + 1) + (xcd - r) * q) + i;

    int idx = wb * 256 + threadIdx.x;
    if (idx >= total_threads) return;

    const int TX = W_ / 4;   // 240
    const int HY = H_ / 4;   // 135
    int tx  = idx % TX;
    int t   = idx / TX;
    int ly4 = t % HY;
    int nc  = t / HY;            // n*C_ + c  in [0,12)
    int n   = nc / C_;
    int lx0 = tx * 4;
    int ly0 = ly4 * 4;           // first low-res row of the quad

    float jx = jitter[2 * n + 0];
    float jy = jitter[2 * n + 1];
    int jnx = (int)floorf(jx * 2.0f);
    int jny = (int)floorf(jy * 2.0f);
    int bjx = (int)floorf(jitter[0] * 2.0f);   // beta lattice uses batch-0 jitter
    int bjy = (int)floorf(jitter[1] * 2.0f);
    bool zcoin = (jnx == bjx) && (jny == bjy); // z-lattice coincides with beta-lattice

    const float* fp = frame + (size_t)nc * (H_ * W_);

    int cL = (lx0 > 0)      ? lx0 - 1 : 0;
    int cR = (lx0 + 4 < W_) ? lx0 + 4 : W_ - 1;

    // ---- 6x6 clamped window (18 load insts, all issued up front for max MLP)
    float w[6][6];
    #pragma unroll
    for (int k = 0; k < 6; ++k) {
        int row = ly0 - 1 + k;
        row = (row < 0) ? 0 : ((row > H_ - 1) ? H_ - 1 : row);
        const float* rp = fp + row * W_;
        f32x4 m = *(const f32x4*)(rp + lx0);
        w[k][0] = rp[cL];
        w[k][1] = m.x; w[k][2] = m.y; w[k][3] = m.z; w[k][4] = m.w;
        w[k][5] = rp[cR];
    }

    // ---- 3x3 min/max pools for 4 low-res rows x 4 cols
    float vmax[4][4], vmin[4][4];
    #pragma unroll
    for (int h = 0; h < 4; ++h) {
        float cmax[6], cmin[6];
        #pragma unroll
        for (int j = 0; j < 6; ++j) {
            cmax[j] = fmaxf(fmaxf(w[h][j], w[h+1][j]), w[h+2][j]);
            cmin[j] = fminf(fminf(w[h][j], w[h+1][j]), w[h+2][j]);
        }
        #pragma unroll
        for (int p = 0; p < 4; ++p) {
            vmax[h][p] = fmaxf(fmaxf(cmax[p], cmax[p+1]), cmax[p+2]);
            vmin[h][p] = fminf(fminf(cmin[p], cmin[p+1]), cmin[p+2]);
        }
    }

    // ---- x-grid constants per output-column parity (exact reference op order)
    float wx_[2]; bool dxm1_[2];
    #pragma unroll
    for (int par = 0; par < 2; ++par) {
        int ox = 8 * tx + par;
        float xs = (2.0f * (float)ox + 1.0f) / (float)WO_ - 1.0f;
        float gx = xs + 2.0f * (0.5f - jx) / (float)W_;
        float ix = ((gx + 1.0f) * (float)W_ - 1.0f) / 2.0f;
        float x0f = floorf(ix);
        wx_[par]   = ix - x0f;
        dxm1_[par] = ((int)x0f < lx0);   // x0 = m-1 (window shift) vs m
    }
    f32x2 wx2 = { wx_[0], wx_[1] };

    size_t base = (size_t)nc * ((size_t)HO_ * WO_);

    #pragma unroll
    for (int ory = 0; ory < 8; ++ory) {
        const int h = ory >> 1;           // low-res row index within quad (static)
        int lr = ly0 + h;
        int oy = 8 * ly4 + ory;
        float ysv = (2.0f * (float)oy + 1.0f) / (float)HO_ - 1.0f;
        float gy = ysv + 2.0f * (0.5f - jy) / (float)H_;
        float iy = ((gy + 1.0f) * (float)H_ - 1.0f) / 2.0f;
        float y0f = floorf(iy);
        float wy  = iy - y0f;
        bool up = ((int)y0f < lr);   // y0 row = lr-1 (w[h]) else lr (w[h+1])

        // y-blend first (wy, up image-uniform; rows static per ory after unroll)
        float brow[6];
        #pragma unroll
        for (int j = 0; j < 6; ++j) {
            float t0 = up ? w[h][j]     : w[h+1][j];
            float t1 = up ? w[h+1][j]   : w[h+2][j];
            brow[j] = t0 + wy * (t1 - t0);
        }
        // parity-shifted 5-wide views: s[j] = brow[j + (dm ? 0 : 1)]
        float s0[5], s1[5];
        #pragma unroll
        for (int j = 0; j < 5; ++j) {
            s0[j] = dxm1_[0] ? brow[j] : brow[j + 1];
            s1[j] = dxm1_[1] ? brow[j] : brow[j + 1];
        }

        bool rowb = ((ory & 1) == bjy);
        float res[8];
        #pragma unroll
        for (int bcol = 0; bcol < 4; ++bcol) {
            f32x2 v0 = { s0[bcol],     s1[bcol]     };
            f32x2 v1 = { s0[bcol + 1], s1[bcol + 1] };
            f32x2 bil = v0 + wx2 * (v1 - v0);
            f32x2 mx = { vmax[h][bcol], vmax[h][bcol] };
            f32x2 mn = { vmin[h][bcol], vmin[h][bcol] };
            f32x2 hcl = __builtin_elementwise_max(mn, __builtin_elementwise_min(mx, bil));
            float zv = zcoin ? w[h+1][bcol + 1] : 0.0f;
            res[2*bcol + 0] = (rowb && (bjx == 0)) ? (0.1f * zv + (1.0f - 0.1f) * hcl.x) : hcl.x;
            res[2*bcol + 1] = (rowb && (bjx == 1)) ? (0.1f * zv + (1.0f - 0.1f) * hcl.y) : hcl.y;
        }

        size_t off = base + (size_t)oy * WO_ + (size_t)8 * tx;
        if ((long long)(off + 8) <= out_elems) {   // defensive: never write OOB
            f32x4 lo = { res[0], res[1], res[2], res[3] };
            f32x4 hi = { res[4], res[5], res[6], res[7] };
            *(f32x4*)(out + off)     = lo;
            *(f32x4*)(out + off + 4) = hi;
        }
    }
}

extern "C" void kernel_launch(void* const* d_in, const int* in_sizes, int n_in,
                              void* d_out, int out_size, void* d_ws, size_t ws_size,
                              hipStream_t stream) {
    const float* frame  = (const float*)d_in[0];
    const float* jitter = (const float*)d_in[1];
    float* out = (float*)d_out;

    const int total = N_ * C_ * (H_ / 4) * (W_ / 4);   // 388,800 threads, 64 px each
    const int block = 256;
    const int grid  = (total + block - 1) / block;      // 1519 blocks
    taa_fused_kernel<<<grid, block, 0, stream>>>(frame, jitter, out,
                                                 total, grid, (long long)out_size);
}

// Round 13
// 26.227 us; speedup vs baseline: 1.0533x; 1.0533x over previous
//
#include <hip/hip_runtime.h>
#include <math.h>

#define N_  4
#define C_  3
#define H_  540
#define W_  960
#define HO_ 1080
#define WO_ 1920

typedef float f32x4 __attribute__((ext_vector_type(4)));
typedef float f32x2 __attribute__((ext_vector_type(2)));

// Thread = (n, c, ly3, tx): owns low-res rows 3ly3..3ly3+2 x cols [4tx,4tx+4)
// -> output rows 6ly3..6ly3+5, cols [8tx, 8tx+8): 48 px, 12 f32x4 stores.
// Needs input rows 3ly3-1 .. 3ly3+3 (5 clamped rows x 6 clamped cols).
// w[k] holds input row ly0-1+k; low-res row lr=ly0+h uses pool rows w[h..h+2],
// bilinear rows (w[h],w[h+1]) if up else (w[h+1],w[h+2]), z row = w[h+1].
// Clamped loads make border-excluded 3x3 pools == plain min/max over the window.
//
// Ladder: R2 33.2 | R3 +XCD swizzle 30.0 | R5 nt stores 33.7 (REGR) | R6 8-col
// x-tile 42.0 (REGR - VGPR cliff) | R7 y-blend-first trim 28.0 | R8 packed-f32
// 28.0 (NEUT) | R9 edge shuffles 28.9 (REGR) | R10 y*2 tile 26.7 (WIN) |
// R11 y*4 tile 27.6 (REGR - crossed occupancy step: window36+pools32).
// R13: y*3 tile - 5 rows serve 6 output rows (1.67 vs 2.0 rows/row), live
// state midway (window30+pools24), designed to stay under the 128-VGPR step;
// 2025 blocks exactly (no partial block).
__global__ __launch_bounds__(256) void taa_fused_kernel(
    const float* __restrict__ frame,
    const float* __restrict__ jitter,
    float* __restrict__ out,
    int total_threads, int n_blocks, long long out_elems)
{
    // ---- bijective chunked XCD swizzle (nwg = n_blocks, 8 XCDs)
    int b   = blockIdx.x;
    int q   = n_blocks >> 3, r = n_blocks & 7;
    int xcd = b & 7, i = b >> 3;
    int wb  = (xcd < r ? xcd * (q + 1) : r * (q + 1) + (xcd - r) * q) + i;

    int idx = wb * 256 + threadIdx.x;
    if (idx >= total_threads) return;

    const int TX = W_ / 4;   // 240
    const int HY = H_ / 3;   // 180
    int tx  = idx % TX;
    int t   = idx / TX;
    int ly3 = t % HY;
    int nc  = t / HY;            // n*C_ + c  in [0,12)
    int n   = nc / C_;
    int lx0 = tx * 4;
    int ly0 = ly3 * 3;           // first low-res row of the triple

    float jx = jitter[2 * n + 0];
    float jy = jitter[2 * n + 1];
    int jnx = (int)floorf(jx * 2.0f);
    int jny = (int)floorf(jy * 2.0f);
    int bjx = (int)floorf(jitter[0] * 2.0f);   // beta lattice uses batch-0 jitter
    int bjy = (int)floorf(jitter[1] * 2.0f);
    bool zcoin = (jnx == bjx) && (jny == bjy); // z-lattice coincides with beta-lattice

    const float* fp = frame + (size_t)nc * (H_ * W_);

    int cL = (lx0 > 0)      ? lx0 - 1 : 0;
    int cR = (lx0 + 4 < W_) ? lx0 + 4 : W_ - 1;

    // ---- 5x6 clamped window (15 load insts, issued up front for MLP)
    float w[5][6];
    #pragma unroll
    for (int k = 0; k < 5; ++k) {
        int row = ly0 - 1 + k;
        row = (row < 0) ? 0 : ((row > H_ - 1) ? H_ - 1 : row);
        const float* rp = fp + row * W_;
        f32x4 m = *(const f32x4*)(rp + lx0);
        w[k][0] = rp[cL];
        w[k][1] = m.x; w[k][2] = m.y; w[k][3] = m.z; w[k][4] = m.w;
        w[k][5] = rp[cR];
    }

    // ---- 3x3 min/max pools for 3 low-res rows x 4 cols
    float vmax[3][4], vmin[3][4];
    #pragma unroll
    for (int h = 0; h < 3; ++h) {
        float cmax[6], cmin[6];
        #pragma unroll
        for (int j = 0; j < 6; ++j) {
            cmax[j] = fmaxf(fmaxf(w[h][j], w[h+1][j]), w[h+2][j]);
            cmin[j] = fminf(fminf(w[h][j], w[h+1][j]), w[h+2][j]);
        }
        #pragma unroll
        for (int p = 0; p < 4; ++p) {
            vmax[h][p] = fmaxf(fmaxf(cmax[p], cmax[p+1]), cmax[p+2]);
            vmin[h][p] = fminf(fminf(cmin[p], cmin[p+1]), cmin[p+2]);
        }
    }

    // ---- x-grid constants per output-column parity (exact reference op order)
    float wx_[2]; bool dxm1_[2];
    #pragma unroll
    for (int par = 0; par < 2; ++par) {
        int ox = 8 * tx + par;
        float xs = (2.0f * (float)ox + 1.0f) / (float)WO_ - 1.0f;
        float gx = xs + 2.0f * (0.5f - jx) / (float)W_;
        float ix = ((gx + 1.0f) * (float)W_ - 1.0f) / 2.0f;
        float x0f = floorf(ix);
        wx_[par]   = ix - x0f;
        dxm1_[par] = ((int)x0f < lx0);   // x0 = m-1 (window shift) vs m
    }
    f32x2 wx2 = { wx_[0], wx_[1] };

    size_t base = (size_t)nc * ((size_t)HO_ * WO_);

    #pragma unroll
    for (int ory = 0; ory < 6; ++ory) {
        const int h = ory >> 1;           // low-res row index within triple (static)
        int lr = ly0 + h;
        int oy = 6 * ly3 + ory;
        float ysv = (2.0f * (float)oy + 1.0f) / (float)HO_ - 1.0f;
        float gy = ysv + 2.0f * (0.5f - jy) / (float)H_;
        float iy = ((gy + 1.0f) * (float)H_ - 1.0f) / 2.0f;
        float y0f = floorf(iy);
        float wy  = iy - y0f;
        bool up = ((int)y0f < lr);   // y0 row = lr-1 (w[h]) else lr (w[h+1])

        // y-blend first (wy, up image-uniform; rows static per ory after unroll)
        float brow[6];
        #pragma unroll
        for (int j = 0; j < 6; ++j) {
            float t0 = up ? w[h][j]   : w[h+1][j];
            float t1 = up ? w[h+1][j] : w[h+2][j];
            brow[j] = t0 + wy * (t1 - t0);
        }
        // parity-shifted 5-wide views: s[j] = brow[j + (dm ? 0 : 1)]
        float s0[5], s1[5];
        #pragma unroll
        for (int j = 0; j < 5; ++j) {
            s0[j] = dxm1_[0] ? brow[j] : brow[j + 1];
            s1[j] = dxm1_[1] ? brow[j] : brow[j + 1];
        }

        bool rowb = ((ory & 1) == bjy);
        float res[8];
        #pragma unroll
        for (int bcol = 0; bcol < 4; ++bcol) {
            f32x2 v0 = { s0[bcol],     s1[bcol]     };
            f32x2 v1 = { s0[bcol + 1], s1[bcol + 1] };
            f32x2 bil = v0 + wx2 * (v1 - v0);
            f32x2 mx = { vmax[h][bcol], vmax[h][bcol] };
            f32x2 mn = { vmin[h][bcol], vmin[h][bcol] };
            f32x2 hcl = __builtin_elementwise_max(mn, __builtin_elementwise_min(mx, bil));
            float zv = zcoin ? w[h+1][bcol + 1] : 0.0f;
            res[2*bcol + 0] = (rowb && (bjx == 0)) ? (0.1f * zv + (1.0f - 0.1f) * hcl.x) : hcl.x;
            res[2*bcol + 1] = (rowb && (bjx == 1)) ? (0.1f * zv + (1.0f - 0.1f) * hcl.y) : hcl.y;
        }

        size_t off = base + (size_t)oy * WO_ + (size_t)8 * tx;
        if ((long long)(off + 8) <= out_elems) {   // defensive: never write OOB
            f32x4 lo = { res[0], res[1], res[2], res[3] };
            f32x4 hi = { res[4], res[5], res[6], res[7] };
            *(f32x4*)(out + off)     = lo;
            *(f32x4*)(out + off + 4) = hi;
        }
    }
}

extern "C" void kernel_launch(void* const* d_in, const int* in_sizes, int n_in,
                              void* d_out, int out_size, void* d_ws, size_t ws_size,
                              hipStream_t stream) {
    const float* frame  = (const float*)d_in[0];
    const float* jitter = (const float*)d_in[1];
    float* out = (float*)d_out;

    const int total = N_ * C_ * (H_ / 3) * (W_ / 4);   // 518,400 threads, 48 px each
    const int block = 256;
    const int grid  = (total + block - 1) / block;      // 2025 blocks exactly
    taa_fused_kernel<<<grid, block, 0, stream>>>(frame, jitter, out,
                                                 total, grid, (long long)out_size);
}

// Round 14
// 26.146 us; speedup vs baseline: 1.0565x; 1.0031x over previous
//
#include <hip/hip_runtime.h>
#include <math.h>

#define N_  4
#define C_  3
#define H_  540
#define W_  960
#define HO_ 1080
#define WO_ 1920

typedef float f32x4 __attribute__((ext_vector_type(4)));
typedef float f32x2 __attribute__((ext_vector_type(2)));

// Thread = (n, c, ly3, tx): owns low-res rows 3ly3..3ly3+2 x low-res cols
// {2tx, 2tx+1} -> output rows 6ly3..6ly3+5, output cols [4tx, 4tx+4):
// 24 px, 6 f32x4 stores -- each store is 16B at 16B lane-stride = a fully
// packed 1KB wave-store (prior kernels: 16B at 32B stride = every cache line
// half-written by two different store insts; this round isolates that).
// Window: 5 clamped rows x 4 cols [2tx-1 .. 2tx+2], loaded as ONE unaligned
// float4 per row (edge threads remap lanes branchlessly).
//
// Ladder: R2 33.2 | R3 +XCD swizzle 30.0 | R5 nt stores 33.7 (REGR) | R6 8-col
// x-tile 42.0 (REGR) | R7 y-blend trim 28.0 | R8 packed-f32 28.0 (NEUT) |
// R9 edge shuffles 28.9 (REGR) | R10 y*2 26.7 | R11 y*4 27.6 (REGR) |
// R13 y*3 26.2 (best). R14: x*2 fully-packed stores, same occupancy bucket.
__global__ __launch_bounds__(256) void taa_fused_kernel(
    const float* __restrict__ frame,
    const float* __restrict__ jitter,
    float* __restrict__ out,
    int total_threads, int n_blocks, long long out_elems)
{
    // ---- bijective chunked XCD swizzle (nwg = n_blocks, 8 XCDs)
    int b   = blockIdx.x;
    int q   = n_blocks >> 3, r = n_blocks & 7;
    int xcd = b & 7, i = b >> 3;
    int wb  = (xcd < r ? xcd * (q + 1) : r * (q + 1) + (xcd - r) * q) + i;

    int idx = wb * 256 + threadIdx.x;
    if (idx >= total_threads) return;

    const int TX = W_ / 2;   // 480
    const int HY = H_ / 3;   // 180
    int tx  = idx % TX;
    int t   = idx / TX;
    int ly3 = t % HY;
    int nc  = t / HY;            // n*C_ + c  in [0,12)
    int n   = nc / C_;
    int ly0 = ly3 * 3;           // first low-res row of the triple

    float jx = jitter[2 * n + 0];
    float jy = jitter[2 * n + 1];
    int jnx = (int)floorf(jx * 2.0f);
    int jny = (int)floorf(jy * 2.0f);
    int bjx = (int)floorf(jitter[0] * 2.0f);   // beta lattice uses batch-0 jitter
    int bjy = (int)floorf(jitter[1] * 2.0f);
    bool zcoin = (jnx == bjx) && (jny == bjy); // z-lattice coincides with beta-lattice

    const float* fp = frame + (size_t)nc * (H_ * W_);

    bool le = (tx == 0), re = (tx == TX - 1);
    // load base col: interior 2tx-1 (unaligned f32x4 covers the whole window);
    // tx==0 -> 0 (remap [x,x,y,z]); tx==TX-1 -> W-4 (remap [y,z,w,w])
    int lb = le ? 0 : (re ? (W_ - 4) : (2 * tx - 1));

    // ---- 5x4 clamped window (5 load insts, issued up front for MLP)
    float w[5][4];
    #pragma unroll
    for (int k = 0; k < 5; ++k) {
        int row = ly0 - 1 + k;
        row = (row < 0) ? 0 : ((row > H_ - 1) ? H_ - 1 : row);
        const float* rp = fp + row * W_;
        f32x4 m = *(const f32x4*)(rp + lb);
        // window cols [2tx-1 .. 2tx+2] with image clamp
        w[k][0] = le ? m.x : (re ? m.y : m.x);
        w[k][1] = le ? m.x : (re ? m.z : m.y);
        w[k][2] = le ? m.y : (re ? m.w : m.z);
        w[k][3] = le ? m.z : m.w;
    }

    // ---- 3x3 min/max pools for 3 low-res rows x 2 cols
    float vmax[3][2], vmin[3][2];
    #pragma unroll
    for (int h = 0; h < 3; ++h) {
        float cmax[4], cmin[4];
        #pragma unroll
        for (int j = 0; j < 4; ++j) {
            cmax[j] = fmaxf(fmaxf(w[h][j], w[h+1][j]), w[h+2][j]);
            cmin[j] = fminf(fminf(w[h][j], w[h+1][j]), w[h+2][j]);
        }
        #pragma unroll
        for (int p = 0; p < 2; ++p) {
            vmax[h][p] = fmaxf(fmaxf(cmax[p], cmax[p+1]), cmax[p+2]);
            vmin[h][p] = fminf(fminf(cmin[p], cmin[p+1]), cmin[p+2]);
        }
    }

    // ---- x-grid constants per output-column parity (exact reference op order)
    float wx_[2]; bool dxm1_[2];
    #pragma unroll
    for (int par = 0; par < 2; ++par) {
        int ox = 4 * tx + par;
        float xs = (2.0f * (float)ox + 1.0f) / (float)WO_ - 1.0f;
        float gx = xs + 2.0f * (0.5f - jx) / (float)W_;
        float ix = ((gx + 1.0f) * (float)W_ - 1.0f) / 2.0f;
        float x0f = floorf(ix);
        wx_[par]   = ix - x0f;
        dxm1_[par] = ((int)x0f < 2 * tx);   // x0 = m-1 (window shift) vs m
    }
    f32x2 wx2 = { wx_[0], wx_[1] };

    size_t base = (size_t)nc * ((size_t)HO_ * WO_);

    #pragma unroll
    for (int ory = 0; ory < 6; ++ory) {
        const int h = ory >> 1;           // low-res row index within triple (static)
        int lr = ly0 + h;
        int oy = 6 * ly3 + ory;
        float ysv = (2.0f * (float)oy + 1.0f) / (float)HO_ - 1.0f;
        float gy = ysv + 2.0f * (0.5f - jy) / (float)H_;
        float iy = ((gy + 1.0f) * (float)H_ - 1.0f) / 2.0f;
        float y0f = floorf(iy);
        float wy  = iy - y0f;
        bool up = ((int)y0f < lr);   // y0 row = lr-1 (w[h]) else lr (w[h+1])

        // y-blend first (wy, up image-uniform; rows static per ory after unroll)
        float brow[4];
        #pragma unroll
        for (int j = 0; j < 4; ++j) {
            float t0 = up ? w[h][j]   : w[h+1][j];
            float t1 = up ? w[h+1][j] : w[h+2][j];
            brow[j] = t0 + wy * (t1 - t0);
        }
        // parity-shifted 3-wide views: s[j] = brow[j + (dm ? 0 : 1)]
        float s0[3], s1[3];
        #pragma unroll
        for (int j = 0; j < 3; ++j) {
            s0[j] = dxm1_[0] ? brow[j] : brow[j + 1];
            s1[j] = dxm1_[1] ? brow[j] : brow[j + 1];
        }

        bool rowb = ((ory & 1) == bjy);
        float res[4];
        #pragma unroll
        for (int bcol = 0; bcol < 2; ++bcol) {
            f32x2 v0 = { s0[bcol],     s1[bcol]     };
            f32x2 v1 = { s0[bcol + 1], s1[bcol + 1] };
            f32x2 bil = v0 + wx2 * (v1 - v0);
            f32x2 mx = { vmax[h][bcol], vmax[h][bcol] };
            f32x2 mn = { vmin[h][bcol], vmin[h][bcol] };
            f32x2 hcl = __builtin_elementwise_max(mn, __builtin_elementwise_min(mx, bil));
            float zv = zcoin ? w[h+1][bcol + 1] : 0.0f;
            res[2*bcol + 0] = (rowb && (bjx == 0)) ? (0.1f * zv + (1.0f - 0.1f) * hcl.x) : hcl.x;
            res[2*bcol + 1] = (rowb && (bjx == 1)) ? (0.1f * zv + (1.0f - 0.1f) * hcl.y) : hcl.y;
        }

        size_t off = base + (size_t)oy * WO_ + (size_t)4 * tx;
        if ((long long)(off + 4) <= out_elems) {   // defensive: never write OOB
            f32x4 o = { res[0], res[1], res[2], res[3] };
            *(f32x4*)(out + off) = o;   // 16B at 16B lane-stride: fully packed
        }
    }
}

extern "C" void kernel_launch(void* const* d_in, const int* in_sizes, int n_in,
                              void* d_out, int out_size, void* d_ws, size_t ws_size,
                              hipStream_t stream) {
    const float* frame  = (const float*)d_in[0];
    const float* jitter = (const float*)d_in[1];
    float* out = (float*)d_out;

    const int total = N_ * C_ * (H_ / 3) * (W_ / 2);   // 2,073,600 threads, 24 px each
    const int block = 256;
    const int grid  = (total + block - 1) / block;      // 8100 blocks exactly
    taa_fused_kernel<<<grid, block, 0, stream>>>(frame, jitter, out,
                                                 total, grid, (long long)out_size);
}